// Round 15
// baseline (373.528 us; speedup 1.0000x reference)
//
#include <hip/hip_runtime.h>
#include <hip/hip_bf16.h>
#include <math.h>

// Problem constants (from reference)
#define B_SZ   128
#define HDIM   256
#define NG     1280     // 5*H
#define NNODES 1023
#define VOCAB  2048

typedef unsigned int uint32;
typedef short  short8v  __attribute__((ext_vector_type(8)));   // 8 x bf16 (4 VGPR)
typedef float  float4v  __attribute__((ext_vector_type(4)));   // MFMA C/D frag

__device__ __forceinline__ float sigm(float x) {
    return 1.0f / (1.0f + __expf(-x));
}
__device__ __forceinline__ float tanh_fast(float x) {
    return 2.0f / (1.0f + __expf(-2.0f * x)) - 1.0f;
}
__device__ __forceinline__ float bf2f(unsigned short u) {
    return __uint_as_float(((uint32)u) << 16);
}
__device__ __forceinline__ unsigned short f2bf(float f) {
    uint32 x = __float_as_uint(f);
    uint32 r = (x + 0x7FFFu + ((x >> 16) & 1u)) >> 16;   // RNE
    return (unsigned short)r;
}

// Async 16B/lane global->LDS DMA. LDS dest = wave-uniform base + lane*16.
__device__ __forceinline__ void dma16(const unsigned short* gptr, unsigned short* lptr) {
    __builtin_amdgcn_global_load_lds(
        (const __attribute__((address_space(1))) void*)gptr,
        (__attribute__((address_space(3))) void*)lptr, 16, 0, 0);
}

// ---------------------------------------------------------------------------
// embb = bf16(emb) : 2048 x 256.  1 MB table -> L2-resident A operand.
// ---------------------------------------------------------------------------
__global__ __launch_bounds__(256) void embb_kernel(
    const float* __restrict__ emb, unsigned short* __restrict__ embb)
{
    const int t = blockIdx.x * 256 + threadIdx.x;
    const float4 v0 = *(const float4*)(emb + (size_t)t * 8);
    const float4 v1 = *(const float4*)(emb + (size_t)t * 8 + 4);
    short8v o;
    o[0] = (short)f2bf(v0.x); o[1] = (short)f2bf(v0.y);
    o[2] = (short)f2bf(v0.z); o[3] = (short)f2bf(v0.w);
    o[4] = (short)f2bf(v1.x); o[5] = (short)f2bf(v1.y);
    o[6] = (short)f2bf(v1.z); o[7] = (short)f2bf(v1.w);
    *(short8v*)(embb + (size_t)t * 8) = o;
}

// ---------------------------------------------------------------------------
// WTf: fragment-ready bf16 repack of [Ul;Ur;Wx] (K=768, N=1280) for MFMA B.
// short8 index = (ng*24 + ks)*64 + lane ; lane = q*16 + c
//   holds B[k = ks*32 + q*8 + j][col = ng*16 + c],  j = 0..7
// Levels use ks 0..15 ([Ul;Ur]); leaf and EW builder use ks 16..23 (Wx).
// ---------------------------------------------------------------------------
__global__ __launch_bounds__(256) void prep_wtf(
    const float* __restrict__ Ul, const float* __restrict__ Ur,
    const float* __restrict__ Wx, unsigned short* __restrict__ WTf)
{
    const int t = blockIdx.x * 256 + threadIdx.x;   // 0..122879
    const int l = t & 63;
    const int q = l >> 4, c = l & 15;
    const int ks = (t >> 6) % 24;
    const int ng = t / (24 * 64);                    // 0..79
    const int col = ng * 16 + c;
    const int k = ks * 32 + q * 8;
    const float* src = (k < 256) ? (Ul + (size_t)k * NG + col)
                     : (k < 512) ? (Ur + (size_t)(k - 256) * NG + col)
                                 : (Wx + (size_t)(k - 512) * NG + col);
    short8v v;
    #pragma unroll
    for (int j = 0; j < 8; ++j) v[j] = (short)f2bf(src[(size_t)j * NG]);
    *(short8v*)(WTf + (size_t)t * 8) = v;
}

// ---------------------------------------------------------------------------
// EWb = bf16(embb @ Wx + b) via MFMA.  Rows are consecutive emb rows.
// ---------------------------------------------------------------------------
__global__ __launch_bounds__(256, 2) void ewb_mfma(
    const unsigned short* __restrict__ WTf, const unsigned short* __restrict__ embb,
    const float* __restrict__ bias, unsigned short* __restrict__ EWb)
{
    __shared__ __align__(16) unsigned short Ab[2][4096];   // 16 KB A dbuf
    __shared__ __align__(16) unsigned short wbE[20480];    // 40 KB: 5 gates x 64 rows x 64 cols

    const int tid  = threadIdx.x;
    const int lane = tid & 63;
    const int w    = tid >> 6;                  // 0..3 = col-tile
    const int quad = lane >> 4, col15 = lane & 15;
    const int jt = blockIdx.x;
    const int rowBase = blockIdx.y * 64;        // emb row
    const int jbase   = jt * 64;

    const unsigned short* agp[2];
    unsigned short* ldst[2];
    #pragma unroll
    for (int t = 0; t < 2; ++t) {
        const int ch = 2 * w + t, sub = ch >> 2, rt = ch & 3;
        const int srow = rowBase + rt * 16 + col15;
        agp[t]  = embb + (size_t)srow * HDIM + sub * 32 + quad * 8;
        ldst[t] = &Ab[0][0] + ch * 512;
    }

    const short8v* WTfv = (const short8v*)WTf;
    uint32 boff[5];
    #pragma unroll
    for (int g = 0; g < 5; ++g)
        boff[g] = ((g * 16 + jt * 4 + w) * 24 + 16) * 64 + lane;   // Wx section

    float4v acc[4][5];
    #pragma unroll
    for (int rt = 0; rt < 4; ++rt)
        #pragma unroll
        for (int g = 0; g < 5; ++g)
            #pragma unroll
            for (int e = 0; e < 4; ++e) acc[rt][g][e] = 0.0f;

    dma16(agp[0], ldst[0]); dma16(agp[1], ldst[1]);
    __syncthreads();

    #pragma unroll
    for (int s = 0; s < 4; ++s) {
        if (s < 3) {
            dma16(agp[0] + (s + 1) * 64, ldst[0] + ((s + 1) & 1) * 4096);
            dma16(agp[1] + (s + 1) * 64, ldst[1] + ((s + 1) & 1) * 4096);
        }
        #pragma unroll
        for (int sub = 0; sub < 2; ++sub) {
            short8v bf[5];
            #pragma unroll
            for (int g = 0; g < 5; ++g) bf[g] = WTfv[boff[g] + (s * 2 + sub) * 64];
            #pragma unroll
            for (int rt = 0; rt < 4; ++rt) {
                const short8v af = *(const short8v*)&Ab[s & 1][(sub * 4 + rt) * 512 + lane * 8];
                #pragma unroll
                for (int g = 0; g < 5; ++g)
                    acc[rt][g] = __builtin_amdgcn_mfma_f32_16x16x32_bf16(
                        af, bf[g], acc[rt][g], 0, 0, 0);
            }
        }
        __syncthreads();
    }

    const int jl = w * 16 + col15;
    const int j  = jbase + jl;
    float bz[5];
    #pragma unroll
    for (int g = 0; g < 5; ++g) bz[g] = bias[g * 256 + j];
    const int jchunk = jl >> 3, jpos = jl & 7;

    #pragma unroll
    for (int rt = 0; rt < 4; ++rt) {
        #pragma unroll
        for (int reg = 0; reg < 4; ++reg) {
            const int rr = rt * 16 + quad * 4 + reg;
            const int roff = ((jchunk + 2 * quad) & 7) * 8 + jpos;  // (rr>>2)&3==quad
            #pragma unroll
            for (int g = 0; g < 5; ++g)
                wbE[(g * 64 + rr) * 64 + roff] = f2bf(acc[rt][g][reg] + bz[g]);
        }
    }
    __syncthreads();

    #pragma unroll
    for (int k2 = 0; k2 < 10; ++k2) {
        const int c = tid + k2 * 256;                // 0..2559
        const int g = c >> 9, rr = (c >> 3) & 63, u = c & 7;
        const int ru = (u + 2 * ((rr >> 2) & 3)) & 7;
        const short8v v = *(const short8v*)&wbE[(g * 64 + rr) * 64 + ru * 8];
        *(short8v*)(EWb + (size_t)(rowBase + rr) * NG + g * 256 + jbase + u * 8) = v;
    }
}

// ---------------------------------------------------------------------------
// Leaf (d=9): gates {i,o,u} = x @ Wx + b, x = embb[tok] (L2-resident).
// R14 form + distance-1 register B prefetch (this round's single change).
// ---------------------------------------------------------------------------
__global__ __launch_bounds__(256, 2) void leaf_kernel(
    const unsigned short* __restrict__ WTf, const unsigned short* __restrict__ embb,
    const float* __restrict__ bias, const int* __restrict__ tokens,
    unsigned short* __restrict__ hdst, unsigned short* __restrict__ cdst)
{
    __shared__ __align__(16) unsigned short Ab[2][4096];   // 2 x 8 KB A dbuf
    __shared__ __align__(16) unsigned short wb[2 * 4096];  // 16 KB h/c writeback

    const int tid  = threadIdx.x;
    const int lane = tid & 63;
    const int w    = tid >> 6;                  // 0..3 = col-tile
    const int quad = lane >> 4, col15 = lane & 15;
    const int jt = blockIdx.x;                  // 0..3 (fastest)
    const int rowBase = blockIdx.y * 64;
    const int jbase   = jt * 64;

    const unsigned short* agp[2];
    unsigned short* ldst[2];
    #pragma unroll
    for (int t = 0; t < 2; ++t) {
        const int ch = 2 * w + t, sub = ch >> 2, rt = ch & 3;
        const int srow = rowBase + rt * 16 + col15;
        const int sb = srow >> 9, si = srow & 511;
        const int stok = tokens[sb * NNODES + 511 + si];
        agp[t]  = embb + (size_t)stok * HDIM + sub * 32 + quad * 8;
        ldst[t] = &Ab[0][0] + ch * 512;
    }

    const short8v* WTfv = (const short8v*)WTf;
    uint32 boff[3];
    boff[0] = ((0 * 16 + jt * 4 + w) * 24 + 16) * 64 + lane;
    boff[1] = ((3 * 16 + jt * 4 + w) * 24 + 16) * 64 + lane;
    boff[2] = ((4 * 16 + jt * 4 + w) * 24 + 16) * 64 + lane;

    float4v acc[4][3];
    #pragma unroll
    for (int rt = 0; rt < 4; ++rt)
        #pragma unroll
        for (int gi = 0; gi < 3; ++gi)
            #pragma unroll
            for (int e = 0; e < 4; ++e) acc[rt][gi][e] = 0.0f;

    short8v bbuf[2][3];
    #pragma unroll
    for (int gi = 0; gi < 3; ++gi) bbuf[0][gi] = WTfv[boff[gi]];

    dma16(agp[0], ldst[0]); dma16(agp[1], ldst[1]);
    __syncthreads();

    #pragma unroll
    for (int s = 0; s < 4; ++s) {
        if (s < 3) {
            dma16(agp[0] + (s + 1) * 64, ldst[0] + ((s + 1) & 1) * 4096);
            dma16(agp[1] + (s + 1) * 64, ldst[1] + ((s + 1) & 1) * 4096);
        }
        #pragma unroll
        for (int sub = 0; sub < 2; ++sub) {
            const int ks = s * 2 + sub;
            if (ks < 7) {
                #pragma unroll
                for (int gi = 0; gi < 3; ++gi)
                    bbuf[(ks + 1) & 1][gi] = WTfv[boff[gi] + (size_t)(ks + 1) * 64];
            }
            #pragma unroll
            for (int rt = 0; rt < 4; ++rt) {
                const short8v af = *(const short8v*)&Ab[s & 1][(sub * 4 + rt) * 512 + lane * 8];
                #pragma unroll
                for (int gi = 0; gi < 3; ++gi)
                    acc[rt][gi] = __builtin_amdgcn_mfma_f32_16x16x32_bf16(
                        af, bbuf[ks & 1][gi], acc[rt][gi], 0, 0, 0);
            }
        }
        __syncthreads();
    }

    // Cell + writeback (C layout: col=lane&15, row=quad*4+reg — verified m89)
    const int jl = w * 16 + col15;
    const int j  = jbase + jl;
    const float b_i = bias[j], b_o = bias[768 + j], b_u = bias[1024 + j];
    const int jchunk = jl >> 3, jpos = jl & 7;

    #pragma unroll
    for (int rt = 0; rt < 4; ++rt) {
        #pragma unroll
        for (int reg = 0; reg < 4; ++reg) {
            const int rr = rt * 16 + quad * 4 + reg;
            const float gi = acc[rt][0][reg] + b_i;
            const float go = acc[rt][1][reg] + b_o;
            const float gu = acc[rt][2][reg] + b_u;
            const float c = sigm(gi) * tanh_fast(gu);
            const float h = sigm(go) * tanh_fast(c);
            const int roff = ((jchunk + 2 * quad) & 7) * 8 + jpos;  // (rr>>2)&3==quad
            wb[rr * 64 + roff]        = f2bf(h);
            wb[4096 + rr * 64 + roff] = f2bf(c);
        }
    }
    __syncthreads();
    #pragma unroll
    for (int k2 = 0; k2 < 4; ++k2) {
        const int c = tid + k2 * 256;                // 0..1023
        const int arr = c >> 9, rr = (c >> 3) & 63, u = c & 7;
        const int ru = (u + 2 * ((rr >> 2) & 3)) & 7;
        const short8v v = *(const short8v*)(wb + (arr * 4096 + rr * 64 + ru * 8));
        unsigned short* dstp = (arr ? cdst : hdst) +
            (size_t)(rowBase + rr) * HDIM + jbase + u * 8;
        *(short8v*)dstp = v;
    }
}

// ---------------------------------------------------------------------------
// Inner level d (8..0): MFMA GEMM [hl|hr](Mx512) @ [Ul;Ur](512x1280) + EW
// gather + LSTM cell.  [R14 form + distance-1 register B prefetch — the
// isolated change this round.  R14 postmortem: B loads were in-step (issue->
// use ~0 distance, ~200 cyc L2 latency exposed per sub-step); prefetch moves
// issue one sub earlier (~194 cyc at 2 waves/SIMD).]
// ---------------------------------------------------------------------------
__global__ __launch_bounds__(256, 2) void level_kernel(
    const unsigned short* __restrict__ WTf, const unsigned short* __restrict__ EWb,
    const int* __restrict__ tokens,
    const unsigned short* __restrict__ hsrc, const unsigned short* __restrict__ csrc,
    unsigned short* __restrict__ hdst, unsigned short* __restrict__ cdst,
    float* __restrict__ out, const int d)
{
    const int n = 1 << d;

    __shared__ __align__(16) unsigned short Ab[2][4096];     // 16 KB A dbuf
    __shared__ __align__(16) unsigned short ews[2560 * 8];   // 40 KB EW gather (reused as wb)
    __shared__ __align__(16) unsigned short cst[1024 * 8];   // 16 KB child c

    const int tid  = threadIdx.x;
    const int lane = tid & 63;
    const int w    = tid >> 6;                  // 0..3 = col-tile
    const int quad = lane >> 4, col15 = lane & 15;
    const int jt = blockIdx.x;                  // 0..3 (fastest)
    const int rowBase = blockIdx.y * 64;
    const int jbase   = jt * 64;

    // ---- A staging: 8 chunks/step (ch = sub*4 + rt); wave w: ch = 2w, 2w+1 ----
    const unsigned short* agp[2];
    unsigned short* ldst[2];
    #pragma unroll
    for (int t = 0; t < 2; ++t) {
        const int ch = 2 * w + t, sub = ch >> 2, rt = ch & 3;
        const int srow = rowBase + rt * 16 + col15;
        agp[t]  = hsrc + (size_t)(2 * srow) * HDIM + sub * 32 + quad * 8;
        ldst[t] = &Ab[0][0] + ch * 512;
    }

    const short8v* WTfv = (const short8v*)WTf;
    uint32 boff[5];
    #pragma unroll
    for (int g = 0; g < 5; ++g)
        boff[g] = ((g * 16 + jt * 4 + w) * 24) * 64 + lane;

    float4v acc[4][5];
    #pragma unroll
    for (int rt = 0; rt < 4; ++rt)
        #pragma unroll
        for (int g = 0; g < 5; ++g)
            #pragma unroll
            for (int e = 0; e < 4; ++e) acc[rt][g][e] = 0.0f;

    short8v bbuf[2][5];
    #pragma unroll
    for (int g = 0; g < 5; ++g) bbuf[0][g] = WTfv[boff[g]];

    dma16(agp[0], ldst[0]); dma16(agp[1], ldst[1]);
    __syncthreads();

    #pragma unroll
    for (int s = 0; s < 8; ++s) {
        if (s < 7) {
            dma16(agp[0] + (s + 1) * 64, ldst[0] + ((s + 1) & 1) * 4096);
            dma16(agp[1] + (s + 1) * 64, ldst[1] + ((s + 1) & 1) * 4096);
        }

        // EWb DMAs (2560 chunks, it=0..9) spread over steps 2..6;
        // child-c DMAs (1024 chunks, k2=0..3) over steps 5..6.
        if (s >= 2 && s <= 6) {
            #pragma unroll
            for (int t2 = 0; t2 < 2; ++t2) {
                const int it = (s - 2) * 2 + t2;         // 0..9
                const int c = tid + it * 256;
                const uint32 row = (uint32)c / 40u;
                const int rem = c - (int)row * 40;
                const int g = rem >> 3, u = rem & 7;
                const int grow = rowBase + (int)row;
                const int tok = tokens[(grow >> d) * NNODES + (n - 1) + (grow & (n - 1))];
                dma16(EWb + (size_t)tok * NG + g * 256 + jbase + u * 8,
                      ews + ((size_t)it * 256 + w * 64) * 8);
            }
            if (s >= 5) {
                #pragma unroll
                for (int t2 = 0; t2 < 2; ++t2) {
                    const int k2 = (s - 5) * 2 + t2;     // 0..3
                    const int c = tid + k2 * 256;
                    const int rr = c >> 4, side = (c >> 3) & 1, u = c & 7;
                    dma16(csrc + (size_t)(2 * (rowBase + rr) + side) * HDIM + jbase + u * 8,
                          cst + ((size_t)k2 * 256 + w * 64) * 8);
                }
            }
        }

        #pragma unroll
        for (int sub = 0; sub < 2; ++sub) {
            const int ks = s * 2 + sub;
            if (ks < 15) {
                #pragma unroll
                for (int g = 0; g < 5; ++g)
                    bbuf[(ks + 1) & 1][g] = WTfv[boff[g] + (size_t)(ks + 1) * 64];
            }
            #pragma unroll
            for (int rt = 0; rt < 4; ++rt) {
                const short8v af = *(const short8v*)&Ab[s & 1][(sub * 4 + rt) * 512 + lane * 8];
                #pragma unroll
                for (int g = 0; g < 5; ++g)
                    acc[rt][g] = __builtin_amdgcn_mfma_f32_16x16x32_bf16(
                        af, bbuf[ks & 1][g], acc[rt][g], 0, 0, 0);
            }
        }
        __syncthreads();
    }

    // ---- Cell math from LDS (C layout col=lane&15, row=quad*4+reg) ----
    const int jl = w * 16 + col15;
    const int j  = jbase + jl;
    float hv[4][4], cv[4][4];
    #pragma unroll
    for (int rt = 0; rt < 4; ++rt) {
        #pragma unroll
        for (int reg = 0; reg < 4; ++reg) {
            const int rr = rt * 16 + quad * 4 + reg;
            const float gi  = acc[rt][0][reg] + bf2f(ews[rr * 320 +       jl]);
            const float gfl = acc[rt][1][reg] + bf2f(ews[rr * 320 +  64 + jl]);
            const float gfr = acc[rt][2][reg] + bf2f(ews[rr * 320 + 128 + jl]);
            const float go  = acc[rt][3][reg] + bf2f(ews[rr * 320 + 192 + jl]);
            const float gu  = acc[rt][4][reg] + bf2f(ews[rr * 320 + 256 + jl]);
            const float cl  = bf2f(cst[rr * 128 +      jl]);
            const float cr  = bf2f(cst[rr * 128 + 64 + jl]);
            const float ii = sigm(gi), fl = sigm(gfl), fr = sigm(gfr), oo = sigm(go);
            const float uu = tanh_fast(gu);
            const float c = ii * uu + fl * cl + fr * cr;
            const float h = oo * tanh_fast(c);
            cv[rt][reg] = c; hv[rt][reg] = h;
            if (d == 0) out[(size_t)(rowBase + rr) * HDIM + j] = h;  // n==1 -> b=row
        }
    }
    __syncthreads();    // ews/cst reads done; reuse ews region for writeback

    const int jchunk = jl >> 3, jpos = jl & 7;
    #pragma unroll
    for (int rt = 0; rt < 4; ++rt) {
        #pragma unroll
        for (int reg = 0; reg < 4; ++reg) {
            const int rr = rt * 16 + quad * 4 + reg;
            const int roff = ((jchunk + 2 * quad) & 7) * 8 + jpos;  // (rr>>2)&3==quad
            ews[rr * 64 + roff]        = f2bf(hv[rt][reg]);
            ews[4096 + rr * 64 + roff] = f2bf(cv[rt][reg]);
        }
    }
    __syncthreads();
    #pragma unroll
    for (int k2 = 0; k2 < 4; ++k2) {
        const int c = tid + k2 * 256;                // 0..1023
        const int arr = c >> 9, rr = (c >> 3) & 63, u = c & 7;
        const int ru = (u + 2 * ((rr >> 2) & 3)) & 7;
        const short8v v = *(const short8v*)(ews + (arr * 4096 + rr * 64 + ru * 8));
        unsigned short* dstp = (arr ? cdst : hdst) +
            (size_t)(rowBase + rr) * HDIM + jbase + u * 8;
        *(short8v*)dstp = v;
    }
}

// ---------------------------------------------------------------------------
extern "C" void kernel_launch(void* const* d_in, const int* in_sizes, int n_in,
                              void* d_out, int out_size, void* d_ws, size_t ws_size,
                              hipStream_t stream)
{
    const int*   tokens = (const int*)d_in[0];
    const float* emb    = (const float*)d_in[1];
    const float* Wx     = (const float*)d_in[2];
    const float* Ul     = (const float*)d_in[3];
    const float* Ur     = (const float*)d_in[4];
    const float* bias   = (const float*)d_in[5];
    float* out = (float*)d_out;

    // Workspace (bf16): EWb 5.24 | embb 1.05 | WTf 1.97 | hA,cA 67.1 | hB,cB 33.6
    const size_t EW_ELEMS  = (size_t)VOCAB * NG;
    const size_t EMB_ELEMS = (size_t)VOCAB * HDIM;
    const size_t WTF_ELEMS = (size_t)80 * 24 * 64 * 8;
    const size_t SLOT_A    = (size_t)512 * B_SZ * HDIM;
    const size_t SLOT_B    = (size_t)256 * B_SZ * HDIM;
    const size_t REQUIRED  = (EW_ELEMS + EMB_ELEMS + WTF_ELEMS + 2 * (SLOT_A + SLOT_B)) * 2;
    if (ws_size < REQUIRED || d_ws == nullptr) return;   // clean fail, not a fault

    char* ws = (char*)d_ws;
    unsigned short* EWb  = (unsigned short*)ws;
    unsigned short* embb = EWb + EW_ELEMS;
    unsigned short* WTf  = embb + EMB_ELEMS;
    unsigned short* hA   = WTf + WTF_ELEMS;
    unsigned short* cA   = hA + SLOT_A;
    unsigned short* hB   = cA + SLOT_A;
    unsigned short* cB   = hB + SLOT_B;

    embb_kernel<<<dim3(256), 256, 0, stream>>>(emb, embb);
    prep_wtf<<<dim3(480), 256, 0, stream>>>(Ul, Ur, Wx, WTf);
    ewb_mfma<<<dim3(4, 32), 256, 0, stream>>>(WTf, embb, bias, EWb);

    // Leaf d=9 -> slot A (row-major r = b*512 + i); 64-row tiles
    leaf_kernel<<<dim3(4, 1024), 256, 0, stream>>>(WTf, embb, bias, tokens, hA, cA);

    // Levels d=8..0 (jt fastest; 64-row tiles -> NRB = 2<<d)
    for (int d = 8; d >= 0; --d) {
        const int NRB = 2 << d;
        const bool evenD = ((d & 1) == 0);
        const unsigned short* hs = evenD ? hA : hB;
        const unsigned short* cs = evenD ? cA : cB;
        unsigned short* hd = evenD ? hB : hA;
        unsigned short* cd = evenD ? cB : cA;
        level_kernel<<<dim3(4, NRB), 256, 0, stream>>>(
            WTf, EWb, tokens, hs, cs, hd, cd, out, d);
    }
}

// Round 16
// 340.519 us; speedup vs baseline: 1.0969x; 1.0969x over previous
//
#include <hip/hip_runtime.h>
#include <hip/hip_bf16.h>
#include <math.h>

// Problem constants (from reference)
#define B_SZ   128
#define HDIM   256
#define NG     1280     // 5*H
#define NNODES 1023
#define VOCAB  2048

typedef unsigned int uint32;
typedef short  short8v  __attribute__((ext_vector_type(8)));   // 8 x bf16 (4 VGPR)
typedef float  float4v  __attribute__((ext_vector_type(4)));   // MFMA C/D frag

__device__ __forceinline__ float sigm(float x) {
    return 1.0f / (1.0f + __expf(-x));
}
__device__ __forceinline__ float tanh_fast(float x) {
    return 2.0f / (1.0f + __expf(-2.0f * x)) - 1.0f;
}
__device__ __forceinline__ float bf2f(unsigned short u) {
    return __uint_as_float(((uint32)u) << 16);
}
__device__ __forceinline__ unsigned short f2bf(float f) {
    uint32 x = __float_as_uint(f);
    uint32 r = (x + 0x7FFFu + ((x >> 16) & 1u)) >> 16;   // RNE
    return (unsigned short)r;
}

// Async 16B/lane global->LDS DMA. LDS dest = wave-uniform base + lane*16.
__device__ __forceinline__ void dma16(const unsigned short* gptr, unsigned short* lptr) {
    __builtin_amdgcn_global_load_lds(
        (const __attribute__((address_space(1))) void*)gptr,
        (__attribute__((address_space(3))) void*)lptr, 16, 0, 0);
}

// ---------------------------------------------------------------------------
// embb = bf16(emb) : 2048 x 256.  A-operand for the EW builder.
// ---------------------------------------------------------------------------
__global__ __launch_bounds__(256) void embb_kernel(
    const float* __restrict__ emb, unsigned short* __restrict__ embb)
{
    const int t = blockIdx.x * 256 + threadIdx.x;
    const float4 v0 = *(const float4*)(emb + (size_t)t * 8);
    const float4 v1 = *(const float4*)(emb + (size_t)t * 8 + 4);
    short8v o;
    o[0] = (short)f2bf(v0.x); o[1] = (short)f2bf(v0.y);
    o[2] = (short)f2bf(v0.z); o[3] = (short)f2bf(v0.w);
    o[4] = (short)f2bf(v1.x); o[5] = (short)f2bf(v1.y);
    o[6] = (short)f2bf(v1.z); o[7] = (short)f2bf(v1.w);
    *(short8v*)(embb + (size_t)t * 8) = o;
}

// ---------------------------------------------------------------------------
// WTf: fragment-ready bf16 repack of [Ul;Ur;Wx] (K=768, N=1280) for MFMA B.
// short8 index = (ng*24 + ks)*64 + lane ; lane = q*16 + c
//   holds B[k = ks*32 + q*8 + j][col = ng*16 + c],  j = 0..7
// Levels use ks 0..15 ([Ul;Ur]); the EW builder uses ks 16..23 (Wx).
// ---------------------------------------------------------------------------
__global__ __launch_bounds__(256) void prep_wtf(
    const float* __restrict__ Ul, const float* __restrict__ Ur,
    const float* __restrict__ Wx, unsigned short* __restrict__ WTf)
{
    const int t = blockIdx.x * 256 + threadIdx.x;   // 0..122879
    const int l = t & 63;
    const int q = l >> 4, c = l & 15;
    const int ks = (t >> 6) % 24;
    const int ng = t / (24 * 64);                    // 0..79
    const int col = ng * 16 + c;
    const int k = ks * 32 + q * 8;
    const float* src = (k < 256) ? (Ul + (size_t)k * NG + col)
                     : (k < 512) ? (Ur + (size_t)(k - 256) * NG + col)
                                 : (Wx + (size_t)(k - 512) * NG + col);
    short8v v;
    #pragma unroll
    for (int j = 0; j < 8; ++j) v[j] = (short)f2bf(src[(size_t)j * NG]);
    *(short8v*)(WTf + (size_t)t * 8) = v;
}

// ---------------------------------------------------------------------------
// EWb = bf16(embb @ Wx + b) via MFMA.  Rows are consecutive emb rows.
// ---------------------------------------------------------------------------
__global__ __launch_bounds__(256, 2) void ewb_mfma(
    const unsigned short* __restrict__ WTf, const unsigned short* __restrict__ embb,
    const float* __restrict__ bias, unsigned short* __restrict__ EWb)
{
    __shared__ __align__(16) unsigned short Ab[2][4096];   // 16 KB A dbuf
    __shared__ __align__(16) unsigned short wbE[20480];    // 40 KB: 5 gates x 64 rows x 64 cols

    const int tid  = threadIdx.x;
    const int lane = tid & 63;
    const int w    = tid >> 6;                  // 0..3 = col-tile
    const int quad = lane >> 4, col15 = lane & 15;
    const int jt = blockIdx.x;
    const int rowBase = blockIdx.y * 64;        // emb row
    const int jbase   = jt * 64;

    const unsigned short* agp[2];
    unsigned short* ldst[2];
    #pragma unroll
    for (int t = 0; t < 2; ++t) {
        const int ch = 2 * w + t, sub = ch >> 2, rt = ch & 3;
        const int srow = rowBase + rt * 16 + col15;
        agp[t]  = embb + (size_t)srow * HDIM + sub * 32 + quad * 8;
        ldst[t] = &Ab[0][0] + ch * 512;
    }

    const short8v* WTfv = (const short8v*)WTf;
    uint32 boff[5];
    #pragma unroll
    for (int g = 0; g < 5; ++g)
        boff[g] = ((g * 16 + jt * 4 + w) * 24 + 16) * 64 + lane;   // Wx section

    float4v acc[4][5];
    #pragma unroll
    for (int rt = 0; rt < 4; ++rt)
        #pragma unroll
        for (int g = 0; g < 5; ++g)
            #pragma unroll
            for (int e = 0; e < 4; ++e) acc[rt][g][e] = 0.0f;

    dma16(agp[0], ldst[0]); dma16(agp[1], ldst[1]);
    __syncthreads();

    #pragma unroll
    for (int s = 0; s < 4; ++s) {
        if (s < 3) {
            dma16(agp[0] + (s + 1) * 64, ldst[0] + ((s + 1) & 1) * 4096);
            dma16(agp[1] + (s + 1) * 64, ldst[1] + ((s + 1) & 1) * 4096);
        }
        #pragma unroll
        for (int sub = 0; sub < 2; ++sub) {
            short8v bf[5];
            #pragma unroll
            for (int g = 0; g < 5; ++g) bf[g] = WTfv[boff[g] + (s * 2 + sub) * 64];
            #pragma unroll
            for (int rt = 0; rt < 4; ++rt) {
                const short8v af = *(const short8v*)&Ab[s & 1][(sub * 4 + rt) * 512 + lane * 8];
                #pragma unroll
                for (int g = 0; g < 5; ++g)
                    acc[rt][g] = __builtin_amdgcn_mfma_f32_16x16x32_bf16(
                        af, bf[g], acc[rt][g], 0, 0, 0);
            }
        }
        __syncthreads();
    }

    const int jl = w * 16 + col15;
    const int j  = jbase + jl;
    float bz[5];
    #pragma unroll
    for (int g = 0; g < 5; ++g) bz[g] = bias[g * 256 + j];
    const int jchunk = jl >> 3, jpos = jl & 7;

    #pragma unroll
    for (int rt = 0; rt < 4; ++rt) {
        #pragma unroll
        for (int reg = 0; reg < 4; ++reg) {
            const int rr = rt * 16 + quad * 4 + reg;
            const int roff = ((jchunk + 2 * quad) & 7) * 8 + jpos;  // (rr>>2)&3==quad
            #pragma unroll
            for (int g = 0; g < 5; ++g)
                wbE[(g * 64 + rr) * 64 + roff] = f2bf(acc[rt][g][reg] + bz[g]);
        }
    }
    __syncthreads();

    #pragma unroll
    for (int k2 = 0; k2 < 10; ++k2) {
        const int c = tid + k2 * 256;                // 0..2559
        const int g = c >> 9, rr = (c >> 3) & 63, u = c & 7;
        const int ru = (u + 2 * ((rr >> 2) & 3)) & 7;
        const short8v v = *(const short8v*)&wbE[(g * 64 + rr) * 64 + ru * 8];
        *(short8v*)(EWb + (size_t)(rowBase + rr) * NG + g * 256 + jbase + u * 8) = v;
    }
}

// ---------------------------------------------------------------------------
// Leaf-as-table (R15 postmortem insight): leaf h/c depend ONLY on the token.
// Hleaf/Cleaf[2048][256] (2 MB, L2-resident) replace the entire 65k-row leaf
// GEMM + its 67 MB of h/c writes; d=8 gathers children from these tables.
// ---------------------------------------------------------------------------
__global__ __launch_bounds__(256) void leaftab_kernel(
    const unsigned short* __restrict__ EWb,
    unsigned short* __restrict__ Hleaf, unsigned short* __restrict__ Cleaf)
{
    const int t = blockIdx.x * 256 + threadIdx.x;   // 0..524287
    const int tok = t >> 8, j = t & 255;
    const float gi = bf2f(EWb[(size_t)tok * NG + j]);
    const float go = bf2f(EWb[(size_t)tok * NG + 768 + j]);
    const float gu = bf2f(EWb[(size_t)tok * NG + 1024 + j]);
    const float c = sigm(gi) * tanh_fast(gu);
    const float h = sigm(go) * tanh_fast(c);
    Hleaf[t] = f2bf(h);
    Cleaf[t] = f2bf(c);
}

// ---------------------------------------------------------------------------
// Inner level d (8..0): MFMA GEMM [hl|hr](Mx512) @ [Ul;Ur](512x1280) + EW
// gather + LSTM cell.  [R14 form — best measured.]  At d==8 the children are
// leaves: A rows gather from Hleaf[tok] and child-c from Cleaf[tok] (2 MB
// L2-resident tables) instead of the 50 MB hA/cA HBM streams.
// 4 waves: wave = 16-col tile, all 64 rows (B loaded once per block);
// A via async-LDS DMA (BK=64 dbuf); EWb/child-c DMA'd during the K-loop.
// ---------------------------------------------------------------------------
__global__ __launch_bounds__(256, 2) void level_kernel(
    const unsigned short* __restrict__ WTf, const unsigned short* __restrict__ EWb,
    const int* __restrict__ tokens,
    const unsigned short* __restrict__ Hleaf, const unsigned short* __restrict__ Cleaf,
    const unsigned short* __restrict__ hsrc, const unsigned short* __restrict__ csrc,
    unsigned short* __restrict__ hdst, unsigned short* __restrict__ cdst,
    float* __restrict__ out, const int d)
{
    const int n = 1 << d;

    __shared__ __align__(16) unsigned short Ab[2][4096];     // 16 KB A dbuf
    __shared__ __align__(16) unsigned short ews[2560 * 8];   // 40 KB EW gather (reused as wb)
    __shared__ __align__(16) unsigned short cst[1024 * 8];   // 16 KB child c

    const int tid  = threadIdx.x;
    const int lane = tid & 63;
    const int w    = tid >> 6;                  // 0..3 = col-tile
    const int quad = lane >> 4, col15 = lane & 15;
    const int jt = blockIdx.x;                  // 0..3 (fastest)
    const int rowBase = blockIdx.y * 64;
    const int jbase   = jt * 64;

    // ---- A staging: 8 chunks/step (ch = sub*4 + rt); wave w: ch = 2w, 2w+1.
    // agp_lo covers k<256 (left child h), agp_hi covers k>=256 (right child).
    // d<8: children are rows 2r,2r+1 of hsrc (contiguous 1KB span).
    // d==8: children are leaves -> token-indexed rows of Hleaf.
    const unsigned short* agp_lo[2];
    const unsigned short* agp_hi[2];
    unsigned short* ldst[2];
    #pragma unroll
    for (int t = 0; t < 2; ++t) {
        const int ch = 2 * w + t, sub = ch >> 2, rt = ch & 3;
        const int srow = rowBase + rt * 16 + col15;
        if (d == 8) {
            const int b = srow >> 8, i = srow & 255;
            const int tokL = tokens[b * NNODES + 511 + 2 * i];
            const int tokR = tokens[b * NNODES + 512 + 2 * i];
            agp_lo[t] = Hleaf + (size_t)tokL * HDIM + sub * 32 + quad * 8;
            agp_hi[t] = Hleaf + (size_t)tokR * HDIM + sub * 32 + quad * 8;
        } else {
            agp_lo[t] = hsrc + (size_t)(2 * srow) * HDIM + sub * 32 + quad * 8;
            agp_hi[t] = agp_lo[t] + HDIM;
        }
        ldst[t] = &Ab[0][0] + ch * 512;
    }

    const short8v* WTfv = (const short8v*)WTf;
    uint32 boff[5];
    #pragma unroll
    for (int g = 0; g < 5; ++g)
        boff[g] = ((g * 16 + jt * 4 + w) * 24) * 64 + lane;

    float4v acc[4][5];
    #pragma unroll
    for (int rt = 0; rt < 4; ++rt)
        #pragma unroll
        for (int g = 0; g < 5; ++g)
            #pragma unroll
            for (int e = 0; e < 4; ++e) acc[rt][g][e] = 0.0f;

    dma16(agp_lo[0], ldst[0]); dma16(agp_lo[1], ldst[1]);   // step 0 (k<256)
    __syncthreads();

    #pragma unroll
    for (int s = 0; s < 8; ++s) {
        if (s < 7) {
            const int sn = s + 1;
            #pragma unroll
            for (int t = 0; t < 2; ++t) {
                const unsigned short* p = (sn < 4) ? (agp_lo[t] + sn * 64)
                                                   : (agp_hi[t] + (sn - 4) * 64);
                dma16(p, ldst[t] + (sn & 1) * 4096);
            }
        }

        // EWb DMAs (2560 chunks, it=0..9) spread over steps 2..6;
        // child-c DMAs (1024 chunks, k2=0..3) over steps 5..6.
        if (s >= 2 && s <= 6) {
            #pragma unroll
            for (int t2 = 0; t2 < 2; ++t2) {
                const int it = (s - 2) * 2 + t2;         // 0..9
                const int c = tid + it * 256;
                const uint32 row = (uint32)c / 40u;
                const int rem = c - (int)row * 40;
                const int g = rem >> 3, u = rem & 7;
                const int grow = rowBase + (int)row;
                const int tok = tokens[(grow >> d) * NNODES + (n - 1) + (grow & (n - 1))];
                dma16(EWb + (size_t)tok * NG + g * 256 + jbase + u * 8,
                      ews + ((size_t)it * 256 + w * 64) * 8);
            }
            if (s >= 5) {
                #pragma unroll
                for (int t2 = 0; t2 < 2; ++t2) {
                    const int k2 = (s - 5) * 2 + t2;     // 0..3
                    const int c = tid + k2 * 256;
                    const int rr = c >> 4, side = (c >> 3) & 1, u = c & 7;
                    const unsigned short* src;
                    if (d == 8) {
                        const int grow = rowBase + rr;
                        const int b = grow >> 8, i = grow & 255;
                        const int tok = tokens[b * NNODES + 511 + 2 * i + side];
                        src = Cleaf + (size_t)tok * HDIM + jbase + u * 8;
                    } else {
                        src = csrc + (size_t)(2 * (rowBase + rr) + side) * HDIM + jbase + u * 8;
                    }
                    dma16(src, cst + ((size_t)k2 * 256 + w * 64) * 8);
                }
            }
        }

        #pragma unroll
        for (int sub = 0; sub < 2; ++sub) {
            short8v bf[5];
            #pragma unroll
            for (int g = 0; g < 5; ++g) bf[g] = WTfv[boff[g] + (s * 2 + sub) * 64];
            #pragma unroll
            for (int rt = 0; rt < 4; ++rt) {
                const short8v af = *(const short8v*)&Ab[s & 1][(sub * 4 + rt) * 512 + lane * 8];
                #pragma unroll
                for (int g = 0; g < 5; ++g)
                    acc[rt][g] = __builtin_amdgcn_mfma_f32_16x16x32_bf16(
                        af, bf[g], acc[rt][g], 0, 0, 0);
            }
        }
        __syncthreads();
    }

    // ---- Cell math from LDS (C layout col=lane&15, row=quad*4+reg) ----
    const int jl = w * 16 + col15;
    const int j  = jbase + jl;
    float hv[4][4], cv[4][4];
    #pragma unroll
    for (int rt = 0; rt < 4; ++rt) {
        #pragma unroll
        for (int reg = 0; reg < 4; ++reg) {
            const int rr = rt * 16 + quad * 4 + reg;
            const float gi  = acc[rt][0][reg] + bf2f(ews[rr * 320 +       jl]);
            const float gfl = acc[rt][1][reg] + bf2f(ews[rr * 320 +  64 + jl]);
            const float gfr = acc[rt][2][reg] + bf2f(ews[rr * 320 + 128 + jl]);
            const float go  = acc[rt][3][reg] + bf2f(ews[rr * 320 + 192 + jl]);
            const float gu  = acc[rt][4][reg] + bf2f(ews[rr * 320 + 256 + jl]);
            const float cl  = bf2f(cst[rr * 128 +      jl]);
            const float cr  = bf2f(cst[rr * 128 + 64 + jl]);
            const float ii = sigm(gi), fl = sigm(gfl), fr = sigm(gfr), oo = sigm(go);
            const float uu = tanh_fast(gu);
            const float c = ii * uu + fl * cl + fr * cr;
            const float h = oo * tanh_fast(c);
            cv[rt][reg] = c; hv[rt][reg] = h;
            if (d == 0) out[(size_t)(rowBase + rr) * HDIM + j] = h;  // n==1 -> b=row
        }
    }
    __syncthreads();    // ews/cst reads done; reuse ews region for writeback

    const int jchunk = jl >> 3, jpos = jl & 7;
    #pragma unroll
    for (int rt = 0; rt < 4; ++rt) {
        #pragma unroll
        for (int reg = 0; reg < 4; ++reg) {
            const int rr = rt * 16 + quad * 4 + reg;
            const int roff = ((jchunk + 2 * quad) & 7) * 8 + jpos;  // (rr>>2)&3==quad
            ews[rr * 64 + roff]        = f2bf(hv[rt][reg]);
            ews[4096 + rr * 64 + roff] = f2bf(cv[rt][reg]);
        }
    }
    __syncthreads();
    #pragma unroll
    for (int k2 = 0; k2 < 4; ++k2) {
        const int c = tid + k2 * 256;                // 0..1023
        const int arr = c >> 9, rr = (c >> 3) & 63, u = c & 7;
        const int ru = (u + 2 * ((rr >> 2) & 3)) & 7;
        const short8v v = *(const short8v*)(ews + (arr * 4096 + rr * 64 + ru * 8));
        unsigned short* dstp = (arr ? cdst : hdst) +
            (size_t)(rowBase + rr) * HDIM + jbase + u * 8;
        *(short8v*)dstp = v;
    }
}

// ---------------------------------------------------------------------------
extern "C" void kernel_launch(void* const* d_in, const int* in_sizes, int n_in,
                              void* d_out, int out_size, void* d_ws, size_t ws_size,
                              hipStream_t stream)
{
    const int*   tokens = (const int*)d_in[0];
    const float* emb    = (const float*)d_in[1];
    const float* Wx     = (const float*)d_in[2];
    const float* Ul     = (const float*)d_in[3];
    const float* Ur     = (const float*)d_in[4];
    const float* bias   = (const float*)d_in[5];
    float* out = (float*)d_out;

    // Workspace (bf16): EWb 5.24 | embb 1.05 | WTf 1.97 | Hleaf+Cleaf 2.1 |
    // hA,cA 2x8.4 | hB,cB 2x16.8  -> ~61 MB total (was 109).
    const size_t EW_ELEMS  = (size_t)VOCAB * NG;
    const size_t EMB_ELEMS = (size_t)VOCAB * HDIM;
    const size_t WTF_ELEMS = (size_t)80 * 24 * 64 * 8;
    const size_t LT_ELEMS  = (size_t)VOCAB * HDIM;        // each of Hleaf, Cleaf
    const size_t SLOT_A    = (size_t)16384 * HDIM;        // d=7,5,3,1 outputs (max 16384 rows)
    const size_t SLOT_B    = (size_t)32768 * HDIM;        // d=8,6,4,2,0 outputs (max 32768 rows)
    const size_t REQUIRED  = (EW_ELEMS + EMB_ELEMS + WTF_ELEMS + 2 * LT_ELEMS
                              + 2 * (SLOT_A + SLOT_B)) * 2;
    if (ws_size < REQUIRED || d_ws == nullptr) return;   // clean fail, not a fault

    char* ws = (char*)d_ws;
    unsigned short* EWb   = (unsigned short*)ws;
    unsigned short* embb  = EWb + EW_ELEMS;
    unsigned short* WTf   = embb + EMB_ELEMS;
    unsigned short* Hleaf = WTf + WTF_ELEMS;
    unsigned short* Cleaf = Hleaf + LT_ELEMS;
    unsigned short* hA    = Cleaf + LT_ELEMS;
    unsigned short* cA    = hA + SLOT_A;
    unsigned short* hB    = cA + SLOT_A;
    unsigned short* cB    = hB + SLOT_B;

    embb_kernel<<<dim3(256), 256, 0, stream>>>(emb, embb);
    prep_wtf<<<dim3(480), 256, 0, stream>>>(Ul, Ur, Wx, WTf);
    ewb_mfma<<<dim3(4, 32), 256, 0, stream>>>(WTf, embb, bias, EWb);
    leaftab_kernel<<<dim3(2048), 256, 0, stream>>>(EWb, Hleaf, Cleaf);   // replaces leaf GEMM

    // Levels d=8..0 (jt fastest; 64-row tiles -> NRB = 2<<d).
    // d=8 reads children from Hleaf/Cleaf tables; d<8 from the ping-pong slots.
    for (int d = 8; d >= 0; --d) {
        const int NRB = 2 << d;
        const bool evenD = ((d & 1) == 0);
        const unsigned short* hs = evenD ? hA : hB;   // unused at d==8
        const unsigned short* cs = evenD ? cA : cB;
        unsigned short* hd = evenD ? hB : hA;
        unsigned short* cd = evenD ? cB : cA;
        level_kernel<<<dim3(4, NRB), 256, 0, stream>>>(
            WTf, EWb, tokens, Hleaf, Cleaf, hs, cs, hd, cd, out, d);
    }
}